// Round 1
// baseline (1604.203 us; speedup 1.0000x reference)
//
#include <hip/hip_runtime.h>

// RealNVP forward, fused across all 8 coupling layers.  Round 9.
// B=131072, D=64, H=256, L=8. out = y[B*D] ++ logdet[B], fp32.
//
// R8 -> R9: occupancy push.  Evidence from R8 counters: MfmaUtil 18.5 /
// VALUBusy 42 / Occupancy 31.6 -> >50% of cycles neither pipe issues =
// barrier/latency stall with only ~10 waves/CU; WRITE 202 MB vs 34 ideal
// (= ~320 B/thread ~ acc[4][4]+acc3) -> scratch spill still alive at the
// 3-wave/SIMD register cap.  Changes:
//   1. BM 64 -> 32 (n-tiles 4 -> 2): acc 64 -> 32 regs, LDS 51.7 -> 21.5 KB.
//      Register budget now fits 4 waves/SIMD (__launch_bounds__(256,4),
//      cap 128); LDS allows 7 blocks/CU -> occupancy 12 -> 16-20 waves/CU,
//      i.e. 4-5 independent blocks interleaving their barrier drains.
//      Cost: weights re-read 2x (4096 blocks) -- L2-resident, ~12 TB/s agg.
//   2. s3 LDS buffer deleted: writer lane == reader lane (d0 is the same
//      expression in both nets), so s3 lives in 8 f32 regs.  -8.7 KB LDS,
//      -pack/unpack VALU, -2 LDS ops/layer, better precision.
//   3. ep3 scalar-ized: no address-taken float4 indexing (was
//      ((const float*)&b3v)[r] -- a stack-demotion generator), no local
//      om[]/mm4[] arrays.  All component access via named macros.
// Everything else = R8: transposed matmuls, padded linear LDS (act stride
// 264 halfs, xm 72), v_cvt_pkrtz packing, fp16 weights in ws.

#define BATCH    131072
#define DIM      64
#define HID      256
#define NLAYER   8
#define BM       32
#define NT       2          // batch 16-row tiles per wave
#define NTHREADS 256

#define ACT_S 264   // act row stride, halfs (256 + 8)
#define XM_S  72    // xm  row stride, halfs (64 + 8)

typedef _Float16 f16;
typedef __attribute__((ext_vector_type(8))) _Float16 f16x8;
typedef __attribute__((ext_vector_type(4))) _Float16 f16x4;
typedef __attribute__((ext_vector_type(2))) _Float16 f16x2;
typedef __attribute__((ext_vector_type(4))) float    f32x4;

#define TWO_LOG2E 2.8853900817779268f   // 2*log2(e)
#define LOG2E     1.4426950408889634f

__device__ __forceinline__ float tanh_fast(float x) {
  // tanh(x) = 1 - 2/(e^{2x}+1); exact +-1 limits at inf -> no clamps needed.
  float e = __builtin_amdgcn_exp2f(x * TWO_LOG2E);
  return 1.f - 2.f * __builtin_amdgcn_rcpf(e + 1.f);
}

// Pack 4 f32 -> f16x4 with two v_cvt_pkrtz_f16_f32.
__device__ __forceinline__ f16x4 pk4(float a, float b, float c, float d) {
  f16x2 lo = __builtin_bit_cast(f16x2, __builtin_amdgcn_cvt_pkrtz(a, b));
  f16x2 hi = __builtin_bit_cast(f16x2, __builtin_amdgcn_cvt_pkrtz(c, d));
  f16x4 o; o[0] = lo[0]; o[1] = lo[1]; o[2] = hi[0]; o[3] = hi[1];
  return o;
}

// fp32 -> fp16 weight pack, all 6 tensors in one launch.
__global__ void cvt6_kernel(const float* s0, f16* d0, const float* s1, f16* d1,
                            const float* s2, f16* d2, const float* s3, f16* d3,
                            const float* s4, f16* d4, const float* s5, f16* d5) {
  // quad counts: 32768, 131072, 32768, 32768, 131072, 32768 (total 393216)
  int i = blockIdx.x * blockDim.x + threadIdx.x;
  const float* s; f16* d; int base;
  if      (i < 32768)  { s = s0; d = d0; base = 0; }
  else if (i < 163840) { s = s1; d = d1; base = 32768; }
  else if (i < 196608) { s = s2; d = d2; base = 163840; }
  else if (i < 229376) { s = s3; d = d3; base = 196608; }
  else if (i < 360448) { s = s4; d = d4; base = 229376; }
  else                 { s = s5; d = d5; base = 360448; }
  int k = i - base;
  float4 v = ((const float4*)s)[k];
  ((f16x4*)d)[k] = pk4(v.x, v.y, v.z, v.w);
}

__global__ __launch_bounds__(NTHREADS, 4) void flow_kernel(
    const float* __restrict__ x, const float* __restrict__ masks,
    const f16* __restrict__ wS1, const f16* __restrict__ wS2, const f16* __restrict__ wS3,
    const float* __restrict__ sb1, const float* __restrict__ sb2, const float* __restrict__ sb3,
    const float* __restrict__ scl,
    const f16* __restrict__ wT1, const f16* __restrict__ wT2, const f16* __restrict__ wT3,
    const float* __restrict__ tb1, const float* __restrict__ tb2, const float* __restrict__ tb3,
    float* __restrict__ y_out, float* __restrict__ ld_out)
{
  __shared__ __attribute__((aligned(16))) f16 act [BM * ACT_S];   // 16896 B
  __shared__ __attribute__((aligned(16))) f16 xm_s[BM * XM_S];    //  4608 B
  float* ld_red = (float*)xm_s;  // aliased: xm dead by the time logdet reduces

  const int tid  = threadIdx.x;
  const int lane = tid & 63;
  const int wv   = tid >> 6;        // wave 0..3: hidden-quarter (mm1/mm2), D-quarter (mm3)
  const int quad = lane >> 4;
  const int l16  = lane & 15;
  const int row0 = blockIdx.x * BM;
  const int d0   = wv * 16 + quad * 4;   // this lane's D base (4 consecutive)

  // Per-lane state: batch row = n*16+l16, D = d0+r  (mm3 C-layout).
  float yv[NT][4];    // flow state, fp32
  float lda[NT];      // logdet accumulator per n
  float s3r[NT][4];   // s-net output, held in regs across the two nets
  #pragma unroll
  for (int n = 0; n < NT; ++n) {
    const float4 v = *(const float4*)&x[(size_t)(row0 + n * 16 + l16) * DIM + d0];
    yv[n][0] = v.x; yv[n][1] = v.y; yv[n][2] = v.z; yv[n][3] = v.w;
    lda[n] = 0.f;
  }

  const f32x4 fzero = {0.f, 0.f, 0.f, 0.f};

  #pragma unroll 1
  for (int l = 0; l < NLAYER; ++l) {
    const float4 mv = *(const float4*)&masks[l * DIM + d0];   // mask for D=d0..d0+3

    // xm = y*mask -> LDS (B-operand of mm1), one b64 per n
    #pragma unroll
    for (int n = 0; n < NT; ++n)
      *(f16x4*)&xm_s[(n * 16 + l16) * XM_S + d0] =
          pk4(yv[n][0] * mv.x, yv[n][1] * mv.y, yv[n][2] * mv.z, yv[n][3] * mv.w);
    __syncthreads();                                     // (1) xm ready

    #pragma unroll 1
    for (int net = 0; net < 2; ++net) {
      const f16*   W1 = (net ? wT1 : wS1) + l * HID * DIM;
      const f16*   W2 = (net ? wT2 : wS2) + l * HID * HID;
      const f16*   W3 = (net ? wT3 : wS3) + l * DIM * HID;
      const float* b1 = (net ? tb1 : sb1) + l * HID;
      const float* b2 = (net ? tb2 : sb2) + l * HID;
      const float* b3 = (net ? tb3 : sb3) + l * DIM;

      f32x4 acc[4][NT];   // [m = hidden tile][n = batch tile]
      #pragma unroll
      for (int m = 0; m < 4; ++m)
        #pragma unroll
        for (int n = 0; n < NT; ++n) acc[m][n] = fzero;

      // ---- mm1 (transposed): C[h, b] = W1 @ xm^T ----
      // Fixed row bases; kt offsets fold into load immediates.
      #pragma unroll
      for (int kt = 0; kt < 2; ++kt) {
        const int k0 = kt * 32 + quad * 8;
        f16x8 afr[4];
        #pragma unroll
        for (int m = 0; m < 4; ++m)
          afr[m] = *(const f16x8*)&W1[(wv * 64 + m * 16 + l16) * DIM + k0];
        #pragma unroll
        for (int n = 0; n < NT; ++n) {
          const f16x8 bfr = *(const f16x8*)&xm_s[(n * 16 + l16) * XM_S + k0];
          #pragma unroll
          for (int m = 0; m < 4; ++m)
            acc[m][n] = __builtin_amdgcn_mfma_f32_16x16x32_f16(afr[m], bfr, acc[m][n], 0, 0, 0);
        }
      }
      // ep1: act[b, h..h+3] = tanh(. + b1)  -- contiguous b64 per (m,n)
      #pragma unroll
      for (int m = 0; m < 4; ++m) {
        const int   h0  = wv * 64 + m * 16 + quad * 4;
        const float4 bv = *(const float4*)&b1[h0];
        #pragma unroll
        for (int n = 0; n < NT; ++n)
          *(f16x4*)&act[(n * 16 + l16) * ACT_S + h0] =
              pk4(tanh_fast(acc[m][n][0] + bv.x), tanh_fast(acc[m][n][1] + bv.y),
                  tanh_fast(acc[m][n][2] + bv.z), tanh_fast(acc[m][n][3] + bv.w));
      }
      __syncthreads();                                   // (2) h1 ready

      // ---- mm2 (transposed): W2 @ h1^T, residual tanh ----
      #pragma unroll
      for (int m = 0; m < 4; ++m)
        #pragma unroll
        for (int n = 0; n < NT; ++n) acc[m][n] = fzero;
      #pragma unroll 2
      for (int kt = 0; kt < 8; ++kt) {
        const int k0 = kt * 32 + quad * 8;
        f16x8 afr[4];
        #pragma unroll
        for (int m = 0; m < 4; ++m)
          afr[m] = *(const f16x8*)&W2[(wv * 64 + m * 16 + l16) * HID + k0];
        #pragma unroll
        for (int n = 0; n < NT; ++n) {
          const f16x8 bfr = *(const f16x8*)&act[(n * 16 + l16) * ACT_S + k0];
          #pragma unroll
          for (int m = 0; m < 4; ++m)
            acc[m][n] = __builtin_amdgcn_mfma_f32_16x16x32_f16(afr[m], bfr, acc[m][n], 0, 0, 0);
        }
      }
      __syncthreads();                                   // (3) all done reading act
      #pragma unroll
      for (int m = 0; m < 4; ++m) {
        const int   h0  = wv * 64 + m * 16 + quad * 4;
        const float4 bv = *(const float4*)&b2[h0];
        #pragma unroll
        for (int n = 0; n < NT; ++n) {
          f16x4* p = (f16x4*)&act[(n * 16 + l16) * ACT_S + h0];
          const f16x4 prev = *p;                         // own cell (same lane wrote it)
          *p = pk4(tanh_fast(acc[m][n][0] + bv.x + (float)prev[0]),
                   tanh_fast(acc[m][n][1] + bv.y + (float)prev[1]),
                   tanh_fast(acc[m][n][2] + bv.z + (float)prev[2]),
                   tanh_fast(acc[m][n][3] + bv.w + (float)prev[3]));
        }
      }
      __syncthreads();                                   // (4) h2 ready

      // ---- mm3 (transposed): W3 @ h2^T -> C[D, b] ----
      f32x4 acc3[NT];
      #pragma unroll
      for (int n = 0; n < NT; ++n) acc3[n] = fzero;
      #pragma unroll 2
      for (int kt = 0; kt < 8; ++kt) {
        const int k0  = kt * 32 + quad * 8;
        const f16x8 a3 = *(const f16x8*)&W3[(wv * 16 + l16) * HID + k0];
        #pragma unroll
        for (int n = 0; n < NT; ++n) {
          const f16x8 bfr = *(const f16x8*)&act[(n * 16 + l16) * ACT_S + k0];
          acc3[n] = __builtin_amdgcn_mfma_f32_16x16x32_f16(a3, bfr, acc3[n], 0, 0, 0);
        }
      }
      if (net == 0) __syncthreads();   // (5) act free for net1's ep1
      // net1's post-mm3 overwrite of act is guarded by next layer's barrier (1)

      const float4 b3v = *(const float4*)&b3[d0];
      if (net == 0) {
        const float4 sv = *(const float4*)&scl[l * DIM + d0];
        // s3 stays in registers: the SAME lane consumes it in net1's epilogue
        // (d0 is net-invariant), so no LDS round-trip is needed at all.
        #define S3C(n, r, BC, SC, MC) \
          s3r[n][r] = (tanh_fast(acc3[n][r] + (BC)) + yv[n][r] * (MC)) * (SC);
        #pragma unroll
        for (int n = 0; n < NT; ++n) {
          S3C(n, 0, b3v.x, sv.x, mv.x)
          S3C(n, 1, b3v.y, sv.y, mv.y)
          S3C(n, 2, b3v.z, sv.z, mv.z)
          S3C(n, 3, b3v.w, sv.w, mv.w)
        }
        #undef S3C
      } else {
        // ep3-t: all component access through named scalars (no address-taken
        // vector indexing -> nothing the compiler can demote to scratch).
        #define EP3T(n, r, BC, MC) {                                     \
          const float y0 = yv[n][r];                                     \
          const float s  = s3r[n][r];                                    \
          const float om = 1.f - (MC);                                   \
          const float tv = acc3[n][r] + (BC) + y0 * (MC);                \
          const float e  = __builtin_amdgcn_exp2f(s * LOG2E);            \
          yv[n][r] = (MC) * y0 + om * (y0 * e + tv);                     \
          lda[n]  += om * s; }
        #pragma unroll
        for (int n = 0; n < NT; ++n) {
          EP3T(n, 0, b3v.x, mv.x)
          EP3T(n, 1, b3v.y, mv.y)
          EP3T(n, 2, b3v.z, mv.z)
          EP3T(n, 3, b3v.w, mv.w)
        }
        #undef EP3T
      }
    } // net
  } // layers

  // y out: coalesced dwordx4 per n
  #pragma unroll
  for (int n = 0; n < NT; ++n) {
    float4 v; v.x = yv[n][0]; v.y = yv[n][1]; v.z = yv[n][2]; v.w = yv[n][3];
    *(float4*)&y_out[(size_t)(row0 + n * 16 + l16) * DIM + d0] = v;
  }

  // logdet: lda[n] holds this lane's D-slice sum; reduce over quad (shfl),
  // then over waves (LDS, aliased on xm_s).
  float v0 = lda[0], v1 = lda[1];
  v0 += __shfl_xor(v0, 16); v0 += __shfl_xor(v0, 32);
  v1 += __shfl_xor(v1, 16); v1 += __shfl_xor(v1, 32);
  __syncthreads();                   // xm region now safe to reuse
  if (quad == 0) {
    ld_red[(0 * 16 + l16) * 4 + wv] = v0;
    ld_red[(1 * 16 + l16) * 4 + wv] = v1;
  }
  __syncthreads();
  if (tid < BM)
    ld_out[row0 + tid] = ld_red[tid * 4 + 0] + ld_red[tid * 4 + 1]
                       + ld_red[tid * 4 + 2] + ld_red[tid * 4 + 3];
}

extern "C" void kernel_launch(void* const* d_in, const int* in_sizes, int n_in,
                              void* d_out, int out_size, void* d_ws, size_t ws_size,
                              hipStream_t stream) {
  const float* x     = (const float*)d_in[0];
  const float* masks = (const float*)d_in[1];
  const float* sW1f  = (const float*)d_in[2];
  const float* sb1   = (const float*)d_in[3];
  const float* sW2f  = (const float*)d_in[4];
  const float* sb2   = (const float*)d_in[5];
  const float* sW3f  = (const float*)d_in[6];
  const float* sb3   = (const float*)d_in[7];
  const float* scl   = (const float*)d_in[8];
  const float* tW1f  = (const float*)d_in[9];
  const float* tb1   = (const float*)d_in[10];
  const float* tW2f  = (const float*)d_in[11];
  const float* tb2   = (const float*)d_in[12];
  const float* tW3f  = (const float*)d_in[13];
  const float* tb3   = (const float*)d_in[14];
  (void)in_sizes; (void)n_in; (void)out_size; (void)ws_size;

  const int W1SZ = NLAYER * HID * DIM;   // 131072
  const int W2SZ = NLAYER * HID * HID;   // 524288
  const int W3SZ = NLAYER * DIM * HID;   // 131072
  f16* wS1 = (f16*)d_ws;
  f16* wS2 = wS1 + W1SZ;
  f16* wS3 = wS2 + W2SZ;
  f16* wT1 = wS3 + W3SZ;
  f16* wT2 = wT1 + W1SZ;
  f16* wT3 = wT2 + W2SZ;

  // total float4 quads = 393216 -> 1536 blocks x 256
  cvt6_kernel<<<1536, 256, 0, stream>>>(sW1f, wS1, sW2f, wS2, sW3f, wS3,
                                        tW1f, wT1, tW2f, wT2, tW3f, wT3);

  float* y_out  = (float*)d_out;
  float* ld_out = y_out + (size_t)BATCH * DIM;
  flow_kernel<<<BATCH / BM, NTHREADS, 0, stream>>>(
      x, masks, wS1, wS2, wS3, sb1, sb2, sb3, scl,
      wT1, wT2, wT3, tb1, tb2, tb3, y_out, ld_out);
}

// Round 2
// 985.343 us; speedup vs baseline: 1.6281x; 1.6281x over previous
//
#include <hip/hip_runtime.h>

// RealNVP forward, fused across all 8 coupling layers.  Round 10.
// B=131072, D=64, H=256, L=8. out = y[B*D] ++ logdet[B], fp32.
//
// R9 post-mortem: same pipe-busy totals as R8 (MFMA ~178 us, VALU ~420 us)
// but 1.7x wall at HIGHER occupancy -> the kernel is bound by per-phase
// fixed costs (barrier drains, per-phase latency ramp), not issue or
// occupancy.  R9 halved per-phase work at constant barrier count = 2x
// phase events per work -> 1.7x slower.  Lever: FEWER, FATTER phases.
//
// R10: merge the s/t nets (independent given xm) into one skewed 5-phase
// schedule per layer (was 8 phases):
//   I1:[mm1_s; ep1_s; mm1_t]   I2:[ep1_t || mm2_s]   I3:[ep2_s || mm2_t]
//   I4:[ep2_t || mm3_s]        I5:[mm3_t; ep3(s&t in-lane); xm_next]
// - every tanh block is paired in-interval with the other net's MFMA block
//   (separate FUs -> co-issue; was strictly serial in R8)
// - ep3 fuses both nets in-registers: mm3_s/mm3_t give the same (b,d) cell
//   to the same lane -> s3 LDS buffer + its barrier deleted
// - acc[4][4] serially reused s->t (no doubling)
// Cost: act_s and act_t coexist -> LDS 76800 B -> 2 blocks/CU (8 waves).
// Accepted: R9 proved occupancy is not the binding constraint here.
// launch_bounds(256,2): cap 256 regs, no allocator squeeze (R9's trap).
// Everything else = R8: transposed matmuls, padded linear LDS, pk4,
// tanh_fast, fp16 weights in ws.

#define BATCH    131072
#define DIM      64
#define HID      256
#define NLAYER   8
#define BM       64
#define NTHREADS 256

#define ACT_S 264   // act row stride, halfs (256 + 8)
#define XM_S  72    // xm  row stride, halfs (64 + 8)

typedef _Float16 f16;
typedef __attribute__((ext_vector_type(8))) _Float16 f16x8;
typedef __attribute__((ext_vector_type(4))) _Float16 f16x4;
typedef __attribute__((ext_vector_type(2))) _Float16 f16x2;
typedef __attribute__((ext_vector_type(4))) float    f32x4;

#define TWO_LOG2E 2.8853900817779268f   // 2*log2(e)
#define LOG2E     1.4426950408889634f

__device__ __forceinline__ float tanh_fast(float x) {
  // tanh(x) = 1 - 2/(e^{2x}+1); exact +-1 limits at inf -> no clamps needed.
  float e = __builtin_amdgcn_exp2f(x * TWO_LOG2E);
  return 1.f - 2.f * __builtin_amdgcn_rcpf(e + 1.f);
}

// Pack 4 f32 -> f16x4 with two v_cvt_pkrtz_f16_f32.
__device__ __forceinline__ f16x4 pk4(float a, float b, float c, float d) {
  f16x2 lo = __builtin_bit_cast(f16x2, __builtin_amdgcn_cvt_pkrtz(a, b));
  f16x2 hi = __builtin_bit_cast(f16x2, __builtin_amdgcn_cvt_pkrtz(c, d));
  f16x4 o; o[0] = lo[0]; o[1] = lo[1]; o[2] = hi[0]; o[3] = hi[1];
  return o;
}

// fp32 -> fp16 weight pack, all 6 tensors in one launch.
__global__ void cvt6_kernel(const float* s0, f16* d0, const float* s1, f16* d1,
                            const float* s2, f16* d2, const float* s3, f16* d3,
                            const float* s4, f16* d4, const float* s5, f16* d5) {
  // quad counts: 32768, 131072, 32768, 32768, 131072, 32768 (total 393216)
  int i = blockIdx.x * blockDim.x + threadIdx.x;
  const float* s; f16* d; int base;
  if      (i < 32768)  { s = s0; d = d0; base = 0; }
  else if (i < 163840) { s = s1; d = d1; base = 32768; }
  else if (i < 196608) { s = s2; d = d2; base = 163840; }
  else if (i < 229376) { s = s3; d = d3; base = 196608; }
  else if (i < 360448) { s = s4; d = d4; base = 229376; }
  else                 { s = s5; d = d5; base = 360448; }
  int k = i - base;
  float4 v = ((const float4*)s)[k];
  ((f16x4*)d)[k] = pk4(v.x, v.y, v.z, v.w);
}

// ---- per-phase building blocks (macros so LDS addrspace + unroll stay) ----

#define MM1(Wp) do {                                                          \
    _Pragma("unroll")                                                         \
    for (int m = 0; m < 4; ++m)                                               \
      _Pragma("unroll")                                                       \
      for (int n = 0; n < 4; ++n) acc[m][n] = fzero;                          \
    _Pragma("unroll")                                                         \
    for (int kt = 0; kt < 2; ++kt) {                                          \
      const int k0 = kt * 32 + quad * 8;                                      \
      f16x8 afr[4];                                                           \
      _Pragma("unroll")                                                       \
      for (int m = 0; m < 4; ++m)                                             \
        afr[m] = *(const f16x8*)&(Wp)[(wv * 64 + m * 16 + l16) * DIM + k0];   \
      _Pragma("unroll")                                                       \
      for (int n = 0; n < 4; ++n) {                                           \
        const f16x8 bfr = *(const f16x8*)&xm_s[(n * 16 + l16) * XM_S + k0];   \
        _Pragma("unroll")                                                     \
        for (int m = 0; m < 4; ++m)                                           \
          acc[m][n] = __builtin_amdgcn_mfma_f32_16x16x32_f16(afr[m], bfr, acc[m][n], 0, 0, 0); \
      }                                                                       \
    }                                                                         \
  } while (0)

#define EP1(dst, bp) do {                                                     \
    _Pragma("unroll")                                                         \
    for (int m = 0; m < 4; ++m) {                                             \
      const int   h0 = wv * 64 + m * 16 + quad * 4;                           \
      const float4 bv = *(const float4*)&(bp)[h0];                            \
      _Pragma("unroll")                                                       \
      for (int n = 0; n < 4; ++n)                                             \
        *(f16x4*)&(dst)[(n * 16 + l16) * ACT_S + h0] =                        \
            pk4(tanh_fast(acc[m][n][0] + bv.x), tanh_fast(acc[m][n][1] + bv.y), \
                tanh_fast(acc[m][n][2] + bv.z), tanh_fast(acc[m][n][3] + bv.w)); \
    }                                                                         \
  } while (0)

#define MM2(Wp, src) do {                                                     \
    _Pragma("unroll")                                                         \
    for (int m = 0; m < 4; ++m)                                               \
      _Pragma("unroll")                                                       \
      for (int n = 0; n < 4; ++n) acc[m][n] = fzero;                          \
    _Pragma("unroll 2")                                                       \
    for (int kt = 0; kt < 8; ++kt) {                                          \
      const int k0 = kt * 32 + quad * 8;                                      \
      f16x8 afr[4];                                                           \
      _Pragma("unroll")                                                       \
      for (int m = 0; m < 4; ++m)                                             \
        afr[m] = *(const f16x8*)&(Wp)[(wv * 64 + m * 16 + l16) * HID + k0];   \
      _Pragma("unroll")                                                       \
      for (int n = 0; n < 4; ++n) {                                           \
        const f16x8 bfr = *(const f16x8*)&(src)[(n * 16 + l16) * ACT_S + k0]; \
        _Pragma("unroll")                                                     \
        for (int m = 0; m < 4; ++m)                                           \
          acc[m][n] = __builtin_amdgcn_mfma_f32_16x16x32_f16(afr[m], bfr, acc[m][n], 0, 0, 0); \
      }                                                                       \
    }                                                                         \
  } while (0)

#define EP2(dst, bp) do {                                                     \
    _Pragma("unroll")                                                         \
    for (int m = 0; m < 4; ++m) {                                             \
      const int   h0 = wv * 64 + m * 16 + quad * 4;                           \
      const float4 bv = *(const float4*)&(bp)[h0];                            \
      _Pragma("unroll")                                                       \
      for (int n = 0; n < 4; ++n) {                                           \
        f16x4* p = (f16x4*)&(dst)[(n * 16 + l16) * ACT_S + h0];               \
        const f16x4 prev = *p;                       /* own cell */           \
        *p = pk4(tanh_fast(acc[m][n][0] + bv.x + (float)prev[0]),             \
                 tanh_fast(acc[m][n][1] + bv.y + (float)prev[1]),             \
                 tanh_fast(acc[m][n][2] + bv.z + (float)prev[2]),             \
                 tanh_fast(acc[m][n][3] + bv.w + (float)prev[3]));            \
      }                                                                       \
    }                                                                         \
  } while (0)

#define MM3(Wp, src, a3) do {                                                 \
    _Pragma("unroll")                                                         \
    for (int n = 0; n < 4; ++n) (a3)[n] = fzero;                              \
    _Pragma("unroll 2")                                                       \
    for (int kt = 0; kt < 8; ++kt) {                                          \
      const int k0 = kt * 32 + quad * 8;                                      \
      const f16x8 a3f = *(const f16x8*)&(Wp)[(wv * 16 + l16) * HID + k0];     \
      _Pragma("unroll")                                                       \
      for (int n = 0; n < 4; ++n) {                                           \
        const f16x8 bfr = *(const f16x8*)&(src)[(n * 16 + l16) * ACT_S + k0]; \
        (a3)[n] = __builtin_amdgcn_mfma_f32_16x16x32_f16(a3f, bfr, (a3)[n], 0, 0, 0); \
      }                                                                       \
    }                                                                         \
  } while (0)

__global__ __launch_bounds__(NTHREADS, 2) void flow_kernel(
    const float* __restrict__ x, const float* __restrict__ masks,
    const f16* __restrict__ wS1, const f16* __restrict__ wS2, const f16* __restrict__ wS3,
    const float* __restrict__ sb1, const float* __restrict__ sb2, const float* __restrict__ sb3,
    const float* __restrict__ scl,
    const f16* __restrict__ wT1, const f16* __restrict__ wT2, const f16* __restrict__ wT3,
    const float* __restrict__ tb1, const float* __restrict__ tb2, const float* __restrict__ tb3,
    float* __restrict__ y_out, float* __restrict__ ld_out)
{
  __shared__ __attribute__((aligned(16))) f16 act_a[BM * ACT_S];   // 33792 B (s-net)
  __shared__ __attribute__((aligned(16))) f16 act_b[BM * ACT_S];   // 33792 B (t-net)
  __shared__ __attribute__((aligned(16))) f16 xm_s [BM * XM_S];    //  9216 B
  float* ld_red = (float*)xm_s;  // aliased: xm dead by the time logdet reduces

  const int tid  = threadIdx.x;
  const int lane = tid & 63;
  const int wv   = tid >> 6;        // wave 0..3: hidden-quarter (mm1/mm2), D-quarter (mm3)
  const int quad = lane >> 4;
  const int l16  = lane & 15;
  const int row0 = blockIdx.x * BM;
  const int d0   = wv * 16 + quad * 4;   // this lane's D base (4 consecutive)

  // Per-lane state: batch row = n*16+l16, D = d0+r  (mm3 C-layout).
  float yv[4][4];    // flow state, fp32
  float lda[4];      // logdet accumulator per n
  #pragma unroll
  for (int n = 0; n < 4; ++n) {
    const float4 v = *(const float4*)&x[(size_t)(row0 + n * 16 + l16) * DIM + d0];
    yv[n][0] = v.x; yv[n][1] = v.y; yv[n][2] = v.z; yv[n][3] = v.w;
    lda[n] = 0.f;
  }

  const f32x4 fzero = {0.f, 0.f, 0.f, 0.f};

  // layer-0 xm
  float4 mv = *(const float4*)&masks[d0];
  #pragma unroll
  for (int n = 0; n < 4; ++n)
    *(f16x4*)&xm_s[(n * 16 + l16) * XM_S + d0] =
        pk4(yv[n][0] * mv.x, yv[n][1] * mv.y, yv[n][2] * mv.z, yv[n][3] * mv.w);
  __syncthreads();                                     // xm ready

  #pragma unroll 1
  for (int l = 0; l < NLAYER; ++l) {
    const f16* W1s = wS1 + l * HID * DIM;
    const f16* W2s = wS2 + l * HID * HID;
    const f16* W3s = wS3 + l * DIM * HID;
    const f16* W1t = wT1 + l * HID * DIM;
    const f16* W2t = wT2 + l * HID * HID;
    const f16* W3t = wT3 + l * DIM * HID;

    f32x4 acc[4][4];     // reused serially: mm1_s -> mm1_t -> mm2_s -> mm2_t
    f32x4 acc3s[4], acc3t[4];

    // ---- I1: mm1_s ; ep1_s ; mm1_t ----
    MM1(W1s);
    EP1(act_a, sb1 + l * HID);
    MM1(W1t);                     // acc := t-net h1 pre-activation
    __syncthreads();              // b2: act_a(h1_s) ready

    // ---- I2: ep1_t || mm2_s ----
    EP1(act_b, tb1 + l * HID);    // consumes acc (mm1_t), trans pipe
    MM2(W2s, act_a);              // matrix pipe
    __syncthreads();              // b3: all done reading act_a; act_b ready

    // ---- I3: ep2_s || mm2_t ----
    EP2(act_a, sb2 + l * HID);    // consumes acc (mm2_s), in-place h2_s
    MM2(W2t, act_b);
    __syncthreads();              // b4: act_a=h2_s ready; all done reading act_b

    // ---- I4: ep2_t || mm3_s ----
    EP2(act_b, tb2 + l * HID);    // consumes acc (mm2_t), in-place h2_t
    MM3(W3s, act_a, acc3s);
    __syncthreads();              // b5: act_b=h2_t ready

    // ---- I5: mm3_t ; ep3 (both nets, in-lane) ; xm for l+1 ----
    MM3(W3t, act_b, acc3t);

    const float4 b3s = *(const float4*)&sb3[l * DIM + d0];
    const float4 sv  = *(const float4*)&scl[l * DIM + d0];
    const float4 b3t = *(const float4*)&tb3[l * DIM + d0];
    #define EP3(n, r, BS, SC, BT, MC) {                                  \
      const float y0  = yv[n][r];                                        \
      const float xmv = y0 * (MC);                                       \
      const float om  = 1.f - (MC);                                      \
      const float s   = (tanh_fast(acc3s[n][r] + (BS)) + xmv) * (SC);    \
      const float tv  = acc3t[n][r] + (BT) + xmv;                        \
      const float e   = __builtin_amdgcn_exp2f(s * LOG2E);               \
      yv[n][r] = (MC) * y0 + om * (y0 * e + tv);                         \
      lda[n]  += om * s; }
    #pragma unroll
    for (int n = 0; n < 4; ++n) {
      EP3(n, 0, b3s.x, sv.x, b3t.x, mv.x)
      EP3(n, 1, b3s.y, sv.y, b3t.y, mv.y)
      EP3(n, 2, b3s.z, sv.z, b3t.z, mv.z)
      EP3(n, 3, b3s.w, sv.w, b3t.w, mv.w)
    }
    #undef EP3

    if (l + 1 < NLAYER) {
      const float4 mvn = *(const float4*)&masks[(l + 1) * DIM + d0];
      #pragma unroll
      for (int n = 0; n < 4; ++n)
        *(f16x4*)&xm_s[(n * 16 + l16) * XM_S + d0] =
            pk4(yv[n][0] * mvn.x, yv[n][1] * mvn.y, yv[n][2] * mvn.z, yv[n][3] * mvn.w);
      mv = mvn;
    }
    __syncthreads();              // b1': xm ready (l=7: pre-reduction fence)
  } // layers

  // y out: coalesced dwordx4 per n
  #pragma unroll
  for (int n = 0; n < 4; ++n) {
    float4 v; v.x = yv[n][0]; v.y = yv[n][1]; v.z = yv[n][2]; v.w = yv[n][3];
    *(float4*)&y_out[(size_t)(row0 + n * 16 + l16) * DIM + d0] = v;
  }

  // logdet: lda[n] holds this lane's D-slice sum; reduce over quad (shfl),
  // then over waves (LDS, aliased on xm_s -- safe after the loop's last barrier).
  float v0 = lda[0], v1 = lda[1], v2 = lda[2], v3 = lda[3];
  v0 += __shfl_xor(v0, 16); v0 += __shfl_xor(v0, 32);
  v1 += __shfl_xor(v1, 16); v1 += __shfl_xor(v1, 32);
  v2 += __shfl_xor(v2, 16); v2 += __shfl_xor(v2, 32);
  v3 += __shfl_xor(v3, 16); v3 += __shfl_xor(v3, 32);
  if (quad == 0) {
    ld_red[(0 * 16 + l16) * 4 + wv] = v0;
    ld_red[(1 * 16 + l16) * 4 + wv] = v1;
    ld_red[(2 * 16 + l16) * 4 + wv] = v2;
    ld_red[(3 * 16 + l16) * 4 + wv] = v3;
  }
  __syncthreads();
  if (tid < BM)
    ld_out[row0 + tid] = ld_red[tid * 4 + 0] + ld_red[tid * 4 + 1]
                       + ld_red[tid * 4 + 2] + ld_red[tid * 4 + 3];
}

extern "C" void kernel_launch(void* const* d_in, const int* in_sizes, int n_in,
                              void* d_out, int out_size, void* d_ws, size_t ws_size,
                              hipStream_t stream) {
  const float* x     = (const float*)d_in[0];
  const float* masks = (const float*)d_in[1];
  const float* sW1f  = (const float*)d_in[2];
  const float* sb1   = (const float*)d_in[3];
  const float* sW2f  = (const float*)d_in[4];
  const float* sb2   = (const float*)d_in[5];
  const float* sW3f  = (const float*)d_in[6];
  const float* sb3   = (const float*)d_in[7];
  const float* scl   = (const float*)d_in[8];
  const float* tW1f  = (const float*)d_in[9];
  const float* tb1   = (const float*)d_in[10];
  const float* tW2f  = (const float*)d_in[11];
  const float* tb2   = (const float*)d_in[12];
  const float* tW3f  = (const float*)d_in[13];
  const float* tb3   = (const float*)d_in[14];
  (void)in_sizes; (void)n_in; (void)out_size; (void)ws_size;

  const int W1SZ = NLAYER * HID * DIM;   // 131072
  const int W2SZ = NLAYER * HID * HID;   // 524288
  const int W3SZ = NLAYER * DIM * HID;   // 131072
  f16* wS1 = (f16*)d_ws;
  f16* wS2 = wS1 + W1SZ;
  f16* wS3 = wS2 + W2SZ;
  f16* wT1 = wS3 + W3SZ;
  f16* wT2 = wT1 + W1SZ;
  f16* wT3 = wT2 + W2SZ;

  // total float4 quads = 393216 -> 1536 blocks x 256
  cvt6_kernel<<<1536, 256, 0, stream>>>(sW1f, wS1, sW2f, wS2, sW3f, wS3,
                                        tW1f, wT1, tW2f, wT2, tW3f, wT3);

  float* y_out  = (float*)d_out;
  float* ld_out = y_out + (size_t)BATCH * DIM;
  flow_kernel<<<BATCH / BM, NTHREADS, 0, stream>>>(
      x, masks, wS1, wS2, wS3, sb1, sb2, sb3, scl,
      wT1, wT2, wT3, tb1, tb2, tb3, y_out, ld_out);
}